// Round 15
// baseline (57.158 us; speedup 1.0000x reference)
//
#include <hip/hip_runtime.h>
#include <cmath>

#define N_J   44      // 4 delta + 8 theta + 32 gamma
#define KDIM  128
#define NCLS  5
#define NT    3       // n-tiles of 16 (44 padded to 48)
#define WCE_OFF (N_J * KDIM)   // ws offset of padded [48][5] classifier weights

typedef __attribute__((ext_vector_type(8))) short bf16x8;
typedef __attribute__((ext_vector_type(4))) float f32x4;

// ---------------------------------------------------------------------------
__device__ __forceinline__ float fast_tanh(float a) {
    float z = fminf(fabsf(a), 15.0f);
    float e = __expf(2.0f * z);
    float t = fmaf(-2.0f, __builtin_amdgcn_rcpf(e + 1.0f), 1.0f);
    return copysignf(t, a);
}

// round-to-nearest-even f32 -> bf16 bits. PROVEN path (R7/R12/R13 champions).
// R14's inline-asm v_cvt_pk_bf16_f32 produced NaNs — do not reintroduce.
__device__ __forceinline__ short bf16_rne(float f) {
    unsigned u = __builtin_bit_cast(unsigned, f);
    unsigned r = (u + 0x7fffu + ((u >> 16) & 1u)) >> 16;
    return (short)r;
}

// ---------------------------------------------------------------------------
// prep: W_all^T [44][128] f32 at ws[0..5632), Wc_eff padded [48][5] (gamma
// rows scaled by C, rows 44..47 zero) at ws[5632..5872).
__global__ void hc_prep(const float* __restrict__ Wd, const float* __restrict__ Wt,
                        const float* __restrict__ Wg, const float* __restrict__ Wc,
                        float C, float* __restrict__ ws) {
    int tid = blockIdx.x * blockDim.x + threadIdx.x;
    int nthr = gridDim.x * blockDim.x;
    for (int idx = tid; idx < N_J * KDIM; idx += nthr) {
        int j = idx / KDIM, k = idx % KDIM;
        float v;
        if (j < 4)       v = Wd[k * 4  + j];
        else if (j < 12) v = Wt[k * 8  + (j - 4)];
        else             v = Wg[k * 32 + (j - 12)];
        ws[idx] = v;
    }
    for (int idx = tid; idx < 48 * NCLS; idx += nthr) {
        int j = idx / NCLS;
        float v = (j < N_J) ? Wc[idx] * (j >= 12 ? C : 1.0f) : 0.0f;
        ws[WCE_OFF + idx] = v;
    }
}

// ---------------------------------------------------------------------------
// main: R13 champion (56.7us) + ONLY the 1-deep load pipeline (cvt_pk asm
// from R14 removed — it NaN'd). Arithmetic bit-identical to R13.
// Main GEMM: swapped-operand mfma(A=W^T, B=x): lane (g,n) holds
// S[row=n][j=16t+4g+r] in acc[t][r]. Classifier via 2 extra MFMAs:
// D[class=4g+r][xrow=n] — zero shuffles.
// Pipeline: convert raw->av (frees raw), issue NEXT tile's loads, then
// MFMAs+tanh+classifier+store run under ~900cyc of load flight.
__global__ __launch_bounds__(256, 3) void hc_main(
        const float* __restrict__ x, const float* __restrict__ ws,
        const float* __restrict__ bc, float* __restrict__ out, int nrows) {
    const int lane = threadIdx.x & 63;
    const int n    = lane & 15;        // x-row-in-tile / class for A2-frag
    const int g    = lane >> 4;        // k-group / j-subgroup
    const int wave   = (blockIdx.x * blockDim.x + threadIdx.x) >> 6;
    const int nwaves = (gridDim.x * blockDim.x) >> 6;
    const int ntiles = (nrows + 15) / 16;

    // ---- W^T fragments (A-operand): lane holds W^T[j = t*16 + n][k-chunk g]
    bf16x8 Bf[NT][4];
#pragma unroll
    for (int t = 0; t < NT; ++t) {
        const int j = t * 16 + n;
        const bool jv = (j < N_J);
#pragma unroll
        for (int kb = 0; kb < 4; ++kb) {
            float4 q0 = {0,0,0,0}, q1 = {0,0,0,0};
            if (jv) {
                const float4* wp = reinterpret_cast<const float4*>(ws + j * KDIM + kb * 32 + g * 8);
                q0 = wp[0]; q1 = wp[1];
            }
            bf16x8 bb;
            bb[0] = bf16_rne(q0.x); bb[1] = bf16_rne(q0.y);
            bb[2] = bf16_rne(q0.z); bb[3] = bf16_rne(q0.w);
            bb[4] = bf16_rne(q1.x); bb[5] = bf16_rne(q1.y);
            bb[6] = bf16_rne(q1.z); bb[7] = bf16_rne(q1.w);
            Bf[t][kb] = bb;
        }
    }

    // ---- classifier A-fragments: A[class][slot s] = Wce[pi(s)][class] ------
    bf16x8 af0, af1;
    {
        const int cls = n;
#pragma unroll
        for (int i = 0; i < 8; ++i) {
            const int j0 = 16 * (i >> 2) + 4 * g + (i & 3);
            const float v0 = (cls < NCLS) ? ws[WCE_OFF + j0 * NCLS + cls] : 0.0f;
            af0[i] = bf16_rne(v0);
            const int j1 = 32 + 4 * g + i;   // only i<4 valid
            const float v1 = (cls < NCLS && i < 4) ? ws[WCE_OFF + j1 * NCLS + cls] : 0.0f;
            af1[i] = bf16_rne(v1);
        }
    }

    // ---- bias: classes 0-3 (stored by g==0 lanes) and class 4 (g==1) -------
    const float4 bc03 = { bc[0], bc[1], bc[2], bc[3] };
    const float  bc4  = bc[4];

    const f32x4* __restrict__ x4 = reinterpret_cast<const f32x4*>(x);
    f32x4 raw[8];

#define LOAD_RAW(T) do {                                                     \
        const unsigned rr_ = min((unsigned)((T) * 16 + n),                   \
                                 (unsigned)(nrows - 1));                     \
        const f32x4* xp_ = x4 + (size_t)rr_ * 32 + g * 2;                    \
        _Pragma("unroll")                                                    \
        for (int kb_ = 0; kb_ < 4; ++kb_) {                                  \
            raw[2*kb_]     = xp_[kb_ * 8];                                   \
            raw[2*kb_ + 1] = xp_[kb_ * 8 + 1];                               \
        }                                                                    \
    } while (0)

    int tile = wave;
    if (tile < ntiles) LOAD_RAW(tile);

    while (tile < ntiles) {
        // ---- convert this tile's A to bf16 frags (frees raw) ---------------
        bf16x8 av[4];
#pragma unroll
        for (int kb = 0; kb < 4; ++kb) {
#pragma unroll
            for (int i = 0; i < 4; ++i) av[kb][i]     = bf16_rne(raw[2*kb][i]);
#pragma unroll
            for (int i = 0; i < 4; ++i) av[kb][4 + i] = bf16_rne(raw[2*kb+1][i]);
        }

        const int cur = tile;
        const int nxt = tile + nwaves;
        if (nxt < ntiles) LOAD_RAW(nxt);   // in flight across MFMA+epilogue

        f32x4 acc[NT];
#pragma unroll
        for (int t = 0; t < NT; ++t) acc[t] = f32x4{0.0f, 0.0f, 0.0f, 0.0f};
#pragma unroll
        for (int kb = 0; kb < 4; ++kb)
#pragma unroll
            for (int t = 0; t < NT; ++t)
                acc[t] = __builtin_amdgcn_mfma_f32_16x16x32_bf16(Bf[t][kb], av[kb], acc[t], 0, 0, 0);

        // ---- epilogue: tanh (lane-local), classifier via 2 MFMAs -----------
        float th[NT][4];
#pragma unroll
        for (int t = 0; t < NT; ++t)
#pragma unroll
            for (int r = 0; r < 4; ++r)
                th[t][r] = fast_tanh(acc[t][r]);

        bf16x8 tb0, tb1;
#pragma unroll
        for (int i = 0; i < 8; ++i) tb0[i] = bf16_rne(th[i >> 2][i & 3]);
#pragma unroll
        for (int i = 0; i < 8; ++i) tb1[i] = (i < 4) ? bf16_rne(th[2][i]) : (short)0;

        f32x4 acc2 = {0.0f, 0.0f, 0.0f, 0.0f};
        acc2 = __builtin_amdgcn_mfma_f32_16x16x32_bf16(af0, tb0, acc2, 0, 0, 0);
        acc2 = __builtin_amdgcn_mfma_f32_16x16x32_bf16(af1, tb1, acc2, 0, 0, 0);
        // acc2[r] = out-partial for class 4g+r, x-row n

        const int row = cur * 16 + n;
        if (row < nrows) {
            if (g == 0) {
                out[(size_t)row * NCLS + 0] = acc2[0] + bc03.x;
                out[(size_t)row * NCLS + 1] = acc2[1] + bc03.y;
                out[(size_t)row * NCLS + 2] = acc2[2] + bc03.z;
                out[(size_t)row * NCLS + 3] = acc2[3] + bc03.w;
            } else if (g == 1) {
                out[(size_t)row * NCLS + 4] = acc2[0] + bc4;
            }
        }
        tile = nxt;
    }
#undef LOAD_RAW
}

// ---------------------------------------------------------------------------
extern "C" void kernel_launch(void* const* d_in, const int* in_sizes, int n_in,
                              void* d_out, int out_size, void* d_ws, size_t ws_size,
                              hipStream_t stream) {
    const float* x  = (const float*)d_in[0];
    const float* Wd = (const float*)d_in[1];
    const float* Wt = (const float*)d_in[2];
    const float* Wg = (const float*)d_in[3];
    const float* Wc = (const float*)d_in[4];
    const float* bc = (const float*)d_in[5];
    float* out = (float*)d_out;
    const int nrows = in_sizes[0] / KDIM;

    // -------- host: closed-form gamma amplitude scale C (data-independent) ---
    const double dt = 0.01, twopi = 6.283185307179586476925286766559;
    double fd[4], ft[8], pht[8];
    for (int i = 0; i < 4; ++i) fd[i] = 1.0 + 3.0 * (double)i / 3.0;   // 1..4
    for (int i = 0; i < 8; ++i) { ft[i] = 4.0 + 4.0 * (double)i / 7.0; pht[i] = 0.0; }
    double Csum = 0.0;
    for (int k = 0; k < 5; ++k) {
        double s = 0.0, c = 0.0;
        for (int i = 0; i < 4; ++i) { double p = twopi * fd[i] * dt * (double)k; s += sin(p); c += cos(p); }
        double mpd = atan2(s * 0.25, c * 0.25);
        double s2 = 0.0, c2 = 0.0;
        for (int i = 0; i < 8; ++i) { s2 += sin(pht[i]); c2 += cos(pht[i]); }
        double mpt = atan2(s2 * 0.125, c2 * 0.125);
        double pac = 1.0 + 0.3 * cos(mpt);
        Csum += pac * pow(1.0 - dt, 4.0 - (double)k);
        for (int i = 0; i < 8; ++i)
            pht[i] += dt * (twopi * ft[i] + 2.0 * sin(mpd - pht[i]));
    }
    const double Cd = pow(1.0 - dt, 5.0) + dt * Csum;
    const float C = (float)Cd;

    hc_prep<<<23, 256, 0, stream>>>(Wd, Wt, Wg, Wc, C, (float*)d_ws);
    hc_main<<<768, 256, 0, stream>>>(x, (const float*)d_ws, bc, out, nrows);
}